// Round 1
// baseline (776.935 us; speedup 1.0000x reference)
//
#include <hip/hip_runtime.h>
#include <hip/hip_bf16.h>
#include <stdint.h>

#define D_MODEL 1024
#define NHEADS  16
#define DKH     64
#define SEQ     2048
#define BATCH   4
#define MTOT    (BATCH*SEQ)   // 8192

typedef unsigned short u16;
typedef __attribute__((ext_vector_type(8))) unsigned short us8;
typedef __attribute__((ext_vector_type(4))) float f32x4;
typedef __attribute__((ext_vector_type(8))) __bf16 bf16x8;

__device__ __forceinline__ u16 bf16_rne(float f) {
  union { float f; uint32_t u; } v; v.f = f;
  return (u16)((v.u + 0x7FFFu + ((v.u >> 16) & 1u)) >> 16);
}

__device__ __forceinline__ f32x4 mfma16(us8 a, us8 b, f32x4 c) {
  return __builtin_amdgcn_mfma_f32_16x16x32_bf16(
      __builtin_bit_cast(bf16x8, a), __builtin_bit_cast(bf16x8, b), c, 0, 0, 0);
}

__device__ __forceinline__ us8 cvt8(float4 x, float4 y) {
  us8 r;
  r[0] = bf16_rne(x.x); r[1] = bf16_rne(x.y); r[2] = bf16_rne(x.z); r[3] = bf16_rne(x.w);
  r[4] = bf16_rne(y.x); r[5] = bf16_rne(y.y); r[6] = bf16_rne(y.z); r[7] = bf16_rne(y.w);
  return r;
}

// ---------------- transpose+convert weight: W[K][N] f32 -> Wt[N][K] bf16 ----
__global__ __launch_bounds__(256) void transpose_cvt_w(
    const float* __restrict__ W, u16* __restrict__ Wt, int rows, int cols) {
  __shared__ float tile[32][33];
  const int c0 = blockIdx.x * 32, r0 = blockIdx.y * 32;
  const int tx = threadIdx.x & 31, ty = threadIdx.x >> 5;
#pragma unroll
  for (int yy = ty; yy < 32; yy += 8)
    tile[yy][tx] = W[(size_t)(r0 + yy) * cols + c0 + tx];
  __syncthreads();
#pragma unroll
  for (int yy = ty; yy < 32; yy += 8)
    Wt[(size_t)(c0 + yy) * rows + r0 + tx] = bf16_rne(tile[tx][yy]);
}

// ---------------- transpose V: per b, Vp[S][1024] bf16 -> Vt[1024][S] bf16 --
__global__ __launch_bounds__(256) void transpose_v_kernel(
    const u16* __restrict__ Vp, u16* __restrict__ Vt) {
  __shared__ u16 tile[32][33];
  const int b = blockIdx.z;
  const int c0 = blockIdx.x * 32, r0 = blockIdx.y * 32;
  const u16* in = Vp + (size_t)b * SEQ * D_MODEL;
  u16* out = Vt + (size_t)b * D_MODEL * SEQ;
  const int tx = threadIdx.x & 31, ty = threadIdx.x >> 5;
#pragma unroll
  for (int yy = ty; yy < 32; yy += 8)
    tile[yy][tx] = in[(size_t)(r0 + yy) * D_MODEL + c0 + tx];
  __syncthreads();
#pragma unroll
  for (int yy = ty; yy < 32; yy += 8)
    out[(size_t)(c0 + yy) * SEQ + r0 + tx] = tile[tx][yy];
}

// ---------------- GEMM: C[M][N] = A[M][K] * Bt[N][K]^T + bias --------------
// 128x128 tile, BK=32, 4 waves (2x2), 4x4 16x16 fragments per wave.
template <bool AF32, bool F32OUT>
__global__ __launch_bounds__(256) void gemm_bt(
    const void* __restrict__ Av, const u16* __restrict__ Bt,
    const float* __restrict__ bias, void* __restrict__ Cv, int N, int K) {
  __shared__ __align__(16) u16 As[128][32];
  __shared__ __align__(16) u16 Bs[128][32];
  const int m0 = blockIdx.x * 128, n0 = blockIdx.y * 128;
  const int t = threadIdx.x;
  const int lane = t & 63, wave = t >> 6;
  const int wm = wave >> 1, wn = wave & 1;
  const int lrow = lane & 15, lhalf = lane >> 4;
  const int r0 = t >> 2, o0 = (t & 3) << 3;  // staging chunk: row, elem offset

  f32x4 acc[4][4];
#pragma unroll
  for (int i = 0; i < 4; i++)
#pragma unroll
    for (int j = 0; j < 4; j++) acc[i][j] = (f32x4){0.f, 0.f, 0.f, 0.f};

  for (int k0 = 0; k0 < K; k0 += 32) {
    us8 a0, a1, b0, b1;
    if constexpr (AF32) {
      const float* Af = (const float*)Av;
      const float4* p0 = (const float4*)(Af + (size_t)(m0 + r0) * K + k0 + o0);
      const float4* p1 = (const float4*)(Af + (size_t)(m0 + r0 + 64) * K + k0 + o0);
      a0 = cvt8(p0[0], p0[1]);
      a1 = cvt8(p1[0], p1[1]);
    } else {
      const u16* Ab = (const u16*)Av;
      a0 = *(const us8*)(Ab + (size_t)(m0 + r0) * K + k0 + o0);
      a1 = *(const us8*)(Ab + (size_t)(m0 + r0 + 64) * K + k0 + o0);
    }
    b0 = *(const us8*)(Bt + (size_t)(n0 + r0) * K + k0 + o0);
    b1 = *(const us8*)(Bt + (size_t)(n0 + r0 + 64) * K + k0 + o0);
    __syncthreads();  // previous tile fully consumed
    *(us8*)(&As[r0][o0]) = a0;
    *(us8*)(&As[r0 + 64][o0]) = a1;
    *(us8*)(&Bs[r0][o0]) = b0;
    *(us8*)(&Bs[r0 + 64][o0]) = b1;
    __syncthreads();  // tile visible
    us8 af[4], bfr[4];
#pragma unroll
    for (int i = 0; i < 4; i++)
      af[i] = *(const us8*)(&As[wm * 64 + i * 16 + lrow][lhalf * 8]);
#pragma unroll
    for (int j = 0; j < 4; j++)
      bfr[j] = *(const us8*)(&Bs[wn * 64 + j * 16 + lrow][lhalf * 8]);
#pragma unroll
    for (int i = 0; i < 4; i++)
#pragma unroll
      for (int j = 0; j < 4; j++) acc[i][j] = mfma16(af[i], bfr[j], acc[i][j]);
  }

#pragma unroll
  for (int i = 0; i < 4; i++) {
    const int rowb = m0 + wm * 64 + i * 16 + lhalf * 4;
#pragma unroll
    for (int j = 0; j < 4; j++) {
      const int col = n0 + wn * 64 + j * 16 + lrow;
      const float bv = bias[col];
#pragma unroll
      for (int r = 0; r < 4; r++) {
        float v = acc[i][j][r] + bv;
        if constexpr (F32OUT)
          ((float*)Cv)[(size_t)(rowb + r) * N + col] = v;
        else
          ((u16*)Cv)[(size_t)(rowb + r) * N + col] = bf16_rne(v);
      }
    }
  }
}

// ---------------- flash attention ------------------------------------------
// grid (S/64, H, B), 4 waves; wave owns 16 q-rows, j-tile = 32, online softmax.
__global__ __launch_bounds__(256) void attn_fwd(
    const u16* __restrict__ Qp, const u16* __restrict__ Kp,
    const u16* __restrict__ Vt, const float* __restrict__ mask,
    u16* __restrict__ ctx) {
  const int b = blockIdx.z, h = blockIdx.y;
  const int t = threadIdx.x, wave = t >> 6, lane = t & 63;
  const int lrow = lane & 15, lhalf = lane >> 4;
  const int q0 = blockIdx.x * 64 + wave * 16;

  __shared__ __align__(16) u16 Plds[4][16][32];  // per-wave private

  const u16* Qb = Qp + (size_t)(b * SEQ + q0) * D_MODEL + h * DKH;
  const u16* Kb = Kp + (size_t)(b * SEQ) * D_MODEL + h * DKH;
  const u16* Vb = Vt + (size_t)(b * NHEADS + h) * DKH * SEQ;
  const float* mb = mask + (size_t)b * SEQ;

  const us8 qf0 = *(const us8*)(Qb + lrow * D_MODEL + lhalf * 8);
  const us8 qf1 = *(const us8*)(Qb + lrow * D_MODEL + 32 + lhalf * 8);

  float mrow[4], lsum[4];
  f32x4 o[4];
#pragma unroll
  for (int r = 0; r < 4; r++) { mrow[r] = -1e30f; lsum[r] = 0.f; }
#pragma unroll
  for (int d = 0; d < 4; d++) o[d] = (f32x4){0.f, 0.f, 0.f, 0.f};

  for (int j0 = 0; j0 < SEQ; j0 += 32) {
    f32x4 s0 = (f32x4){0.f, 0.f, 0.f, 0.f}, s1 = (f32x4){0.f, 0.f, 0.f, 0.f};
    {
      const u16* kr = Kb + (size_t)(j0 + lrow) * D_MODEL;
      us8 k00 = *(const us8*)(kr + lhalf * 8);
      us8 k01 = *(const us8*)(kr + 32 + lhalf * 8);
      s0 = mfma16(qf0, k00, s0);
      s0 = mfma16(qf1, k01, s0);
      const u16* kr2 = kr + 16 * D_MODEL;
      us8 k10 = *(const us8*)(kr2 + lhalf * 8);
      us8 k11 = *(const us8*)(kr2 + 32 + lhalf * 8);
      s1 = mfma16(qf0, k10, s1);
      s1 = mfma16(qf1, k11, s1);
    }
    const float mv0 = mb[j0 + lrow] * -1e9f;
    const float mv1 = mb[j0 + 16 + lrow] * -1e9f;
    float sc0[4], sc1[4], tmax[4], corr[4], rsum[4];
#pragma unroll
    for (int r = 0; r < 4; r++) {
      sc0[r] = s0[r] * 0.125f + mv0;   // 1/sqrt(64)
      sc1[r] = s1[r] * 0.125f + mv1;
      tmax[r] = fmaxf(sc0[r], sc1[r]);
    }
#pragma unroll
    for (int d = 1; d < 16; d <<= 1)
#pragma unroll
      for (int r = 0; r < 4; r++) tmax[r] = fmaxf(tmax[r], __shfl_xor(tmax[r], d));
#pragma unroll
    for (int r = 0; r < 4; r++) {
      const float mnew = fmaxf(mrow[r], tmax[r]);
      corr[r] = __expf(mrow[r] - mnew);
      const float p0 = __expf(sc0[r] - mnew);
      const float p1 = __expf(sc1[r] - mnew);
      sc0[r] = p0; sc1[r] = p1;
      rsum[r] = p0 + p1;
      mrow[r] = mnew;
    }
#pragma unroll
    for (int d = 1; d < 16; d <<= 1)
#pragma unroll
      for (int r = 0; r < 4; r++) rsum[r] += __shfl_xor(rsum[r], d);
#pragma unroll
    for (int r = 0; r < 4; r++) lsum[r] = lsum[r] * corr[r] + rsum[r];
#pragma unroll
    for (int d = 0; d < 4; d++)
#pragma unroll
      for (int r = 0; r < 4; r++) o[d][r] *= corr[r];
    // P (C-layout) -> LDS -> A-fragment layout
#pragma unroll
    for (int r = 0; r < 4; r++) {
      Plds[wave][lhalf * 4 + r][lrow] = bf16_rne(sc0[r]);
      Plds[wave][lhalf * 4 + r][16 + lrow] = bf16_rne(sc1[r]);
    }
    const us8 pf = *(const us8*)(&Plds[wave][lrow][lhalf * 8]);
#pragma unroll
    for (int d = 0; d < 4; d++) {
      us8 vf = *(const us8*)(Vb + (size_t)(d * 16 + lrow) * SEQ + j0 + lhalf * 8);
      o[d] = mfma16(pf, vf, o[d]);
    }
  }
  u16* op = ctx + (size_t)(b * SEQ + q0) * D_MODEL + h * DKH;
#pragma unroll
  for (int d = 0; d < 4; d++)
#pragma unroll
    for (int r = 0; r < 4; r++) {
      const float v = o[d][r] / lsum[r];
      op[(size_t)(lhalf * 4 + r) * D_MODEL + d * 16 + lrow] = bf16_rne(v);
    }
}

// ---------------------------------------------------------------------------
extern "C" void kernel_launch(void* const* d_in, const int* in_sizes, int n_in,
                              void* d_out, int out_size, void* d_ws, size_t ws_size,
                              hipStream_t stream) {
  const float* query = (const float*)d_in[0];
  const float* key   = (const float*)d_in[1];
  const float* value = (const float*)d_in[2];
  const float* mask  = (const float*)d_in[3];
  const float* Wq = (const float*)d_in[4];  const float* bq = (const float*)d_in[5];
  const float* Wk = (const float*)d_in[6];  const float* bk = (const float*)d_in[7];
  const float* Wv = (const float*)d_in[8];  const float* bv = (const float*)d_in[9];
  const float* Wo = (const float*)d_in[10]; const float* bo = (const float*)d_in[11];
  float* out = (float*)d_out;

  const size_t MB = 1ull << 20;
  char* ws = (char*)d_ws;
  u16* wtq = (u16*)(ws + 0 * MB);
  u16* wtk = (u16*)(ws + 2 * MB);
  u16* wtv = (u16*)(ws + 4 * MB);
  u16* wto = (u16*)(ws + 6 * MB);
  u16* Qp  = (u16*)(ws + 8 * MB);
  u16* Kp  = (u16*)(ws + 24 * MB);
  u16* ctx = (u16*)(ws + 40 * MB);   // total ws use: 56 MB
  // Vp/Vt live in d_out (exactly 32 MB); dead before the final GEMM overwrites.
  u16* Vp = (u16*)d_out;
  u16* Vt = Vp + (size_t)MTOT * D_MODEL;

  transpose_cvt_w<<<dim3(32, 32), 256, 0, stream>>>(Wq, wtq, D_MODEL, D_MODEL);
  transpose_cvt_w<<<dim3(32, 32), 256, 0, stream>>>(Wk, wtk, D_MODEL, D_MODEL);
  transpose_cvt_w<<<dim3(32, 32), 256, 0, stream>>>(Wv, wtv, D_MODEL, D_MODEL);
  transpose_cvt_w<<<dim3(32, 32), 256, 0, stream>>>(Wo, wto, D_MODEL, D_MODEL);

  dim3 ggrid(MTOT / 128, D_MODEL / 128);
  gemm_bt<true, false><<<ggrid, 256, 0, stream>>>((const void*)query, wtq, bq, (void*)Qp, D_MODEL, D_MODEL);
  gemm_bt<true, false><<<ggrid, 256, 0, stream>>>((const void*)key,   wtk, bk, (void*)Kp, D_MODEL, D_MODEL);
  gemm_bt<true, false><<<ggrid, 256, 0, stream>>>((const void*)value, wtv, bv, (void*)Vp, D_MODEL, D_MODEL);

  transpose_v_kernel<<<dim3(D_MODEL / 32, SEQ / 32, BATCH), 256, 0, stream>>>(Vp, Vt);

  attn_fwd<<<dim3(SEQ / 64, NHEADS, BATCH), 256, 0, stream>>>(Qp, Kp, Vt, mask, ctx);

  gemm_bt<false, true><<<ggrid, 256, 0, stream>>>((const void*)ctx, wto, bo, (void*)out, D_MODEL, D_MODEL);
}

// Round 3
// 590.654 us; speedup vs baseline: 1.3154x; 1.3154x over previous
//
#include <hip/hip_runtime.h>
#include <hip/hip_bf16.h>
#include <stdint.h>

#define D_MODEL 1024
#define NHEADS  16
#define DKH     64
#define SEQ     2048
#define BATCH   4
#define MTOT    (BATCH*SEQ)   // 8192

typedef unsigned short u16;
typedef uint32_t u32;
typedef __attribute__((ext_vector_type(8))) unsigned short us8;
typedef __attribute__((ext_vector_type(4))) float f32x4;
typedef __attribute__((ext_vector_type(16))) float f32x16;
typedef __attribute__((ext_vector_type(8))) __bf16 bf16x8;

__device__ __forceinline__ u16 to_bf16(float f) {
  __bf16 h = (__bf16)f;            // RNE fptrunc
  return __builtin_bit_cast(u16, h);
}
__device__ __forceinline__ u32 pack_bf16(float lo, float hi) {
  return (u32)to_bf16(lo) | ((u32)to_bf16(hi) << 16);
}

__device__ __forceinline__ f32x4 mfma16(us8 a, us8 b, f32x4 c) {
  return __builtin_amdgcn_mfma_f32_16x16x32_bf16(
      __builtin_bit_cast(bf16x8, a), __builtin_bit_cast(bf16x8, b), c, 0, 0, 0);
}
__device__ __forceinline__ f32x16 mfma32(us8 a, us8 b, f32x16 c) {
  return __builtin_amdgcn_mfma_f32_32x32x16_bf16(
      __builtin_bit_cast(bf16x8, a), __builtin_bit_cast(bf16x8, b), c, 0, 0, 0);
}

__device__ __forceinline__ us8 cvt8(float4 x, float4 y) {
  us8 r;
  r[0] = to_bf16(x.x); r[1] = to_bf16(x.y); r[2] = to_bf16(x.z); r[3] = to_bf16(x.w);
  r[4] = to_bf16(y.x); r[5] = to_bf16(y.y); r[6] = to_bf16(y.z); r[7] = to_bf16(y.w);
  return r;
}

// ---------------- transpose+convert weight: W[K][N] f32 -> Wt[N][K] bf16 ----
__global__ __launch_bounds__(256) void transpose_cvt_w(
    const float* __restrict__ W, u16* __restrict__ Wt, int rows, int cols) {
  __shared__ float tile[32][33];
  const int c0 = blockIdx.x * 32, r0 = blockIdx.y * 32;
  const int tx = threadIdx.x & 31, ty = threadIdx.x >> 5;
#pragma unroll
  for (int yy = ty; yy < 32; yy += 8)
    tile[yy][tx] = W[(size_t)(r0 + yy) * cols + c0 + tx];
  __syncthreads();
#pragma unroll
  for (int yy = ty; yy < 32; yy += 8)
    Wt[(size_t)(c0 + yy) * rows + r0 + tx] = to_bf16(tile[tx][yy]);
}

// ---------------- transpose V: per b, Vp[S][1024] bf16 -> Vt[1024][S] bf16 --
__global__ __launch_bounds__(256) void transpose_v_kernel(
    const u16* __restrict__ Vp, u16* __restrict__ Vt) {
  __shared__ u16 tile[32][33];
  const int b = blockIdx.z;
  const int c0 = blockIdx.x * 32, r0 = blockIdx.y * 32;
  const u16* in = Vp + (size_t)b * SEQ * D_MODEL;
  u16* out = Vt + (size_t)b * D_MODEL * SEQ;
  const int tx = threadIdx.x & 31, ty = threadIdx.x >> 5;
#pragma unroll
  for (int yy = ty; yy < 32; yy += 8)
    tile[yy][tx] = in[(size_t)(r0 + yy) * D_MODEL + c0 + tx];
  __syncthreads();
#pragma unroll
  for (int yy = ty; yy < 32; yy += 8)
    out[(size_t)(c0 + yy) * SEQ + r0 + tx] = tile[tx][yy];
}

// ---------------- GEMM: C[M][N] = A[M][K] * Bt[N][K]^T + bias --------------
template <bool AF32, bool F32OUT>
__global__ __launch_bounds__(256) void gemm_bt(
    const void* __restrict__ Av, const u16* __restrict__ Bt,
    const float* __restrict__ bias, void* __restrict__ Cv, int N, int K) {
  __shared__ __align__(16) u16 As[128][32];
  __shared__ __align__(16) u16 Bs[128][32];
  const int m0 = blockIdx.x * 128, n0 = blockIdx.y * 128;
  const int t = threadIdx.x;
  const int lane = t & 63, wave = t >> 6;
  const int wm = wave >> 1, wn = wave & 1;
  const int lrow = lane & 15, lhalf = lane >> 4;
  const int r0 = t >> 2, o0 = (t & 3) << 3;

  f32x4 acc[4][4];
#pragma unroll
  for (int i = 0; i < 4; i++)
#pragma unroll
    for (int j = 0; j < 4; j++) acc[i][j] = (f32x4){0.f, 0.f, 0.f, 0.f};

  for (int k0 = 0; k0 < K; k0 += 32) {
    us8 a0, a1, b0, b1;
    if constexpr (AF32) {
      const float* Af = (const float*)Av;
      const float4* p0 = (const float4*)(Af + (size_t)(m0 + r0) * K + k0 + o0);
      const float4* p1 = (const float4*)(Af + (size_t)(m0 + r0 + 64) * K + k0 + o0);
      a0 = cvt8(p0[0], p0[1]);
      a1 = cvt8(p1[0], p1[1]);
    } else {
      const u16* Ab = (const u16*)Av;
      a0 = *(const us8*)(Ab + (size_t)(m0 + r0) * K + k0 + o0);
      a1 = *(const us8*)(Ab + (size_t)(m0 + r0 + 64) * K + k0 + o0);
    }
    b0 = *(const us8*)(Bt + (size_t)(n0 + r0) * K + k0 + o0);
    b1 = *(const us8*)(Bt + (size_t)(n0 + r0 + 64) * K + k0 + o0);
    __syncthreads();
    *(us8*)(&As[r0][o0]) = a0;
    *(us8*)(&As[r0 + 64][o0]) = a1;
    *(us8*)(&Bs[r0][o0]) = b0;
    *(us8*)(&Bs[r0 + 64][o0]) = b1;
    __syncthreads();
    us8 af[4], bfr[4];
#pragma unroll
    for (int i = 0; i < 4; i++)
      af[i] = *(const us8*)(&As[wm * 64 + i * 16 + lrow][lhalf * 8]);
#pragma unroll
    for (int j = 0; j < 4; j++)
      bfr[j] = *(const us8*)(&Bs[wn * 64 + j * 16 + lrow][lhalf * 8]);
#pragma unroll
    for (int i = 0; i < 4; i++)
#pragma unroll
      for (int j = 0; j < 4; j++) acc[i][j] = mfma16(af[i], bfr[j], acc[i][j]);
  }

#pragma unroll
  for (int i = 0; i < 4; i++) {
    const int rowb = m0 + wm * 64 + i * 16 + lhalf * 4;
#pragma unroll
    for (int j = 0; j < 4; j++) {
      const int col = n0 + wn * 64 + j * 16 + lrow;
      const float bv = bias[col];
#pragma unroll
      for (int r = 0; r < 4; r++) {
        float v = acc[i][j][r] + bv;
        if constexpr (F32OUT)
          ((float*)Cv)[(size_t)(rowb + r) * N + col] = v;
        else
          ((u16*)Cv)[(size_t)(rowb + r) * N + col] = to_bf16(v);
      }
    }
  }
}

// ---------------- flash attention, swapped-QK^T 32x32, 1 wave/block --------
// Lane owns q = lane&31; lane and lane^32 hold complementary kv halves.
// S^T = mfma32(K, Q); O^T = mfma32(V^T, P^T) -> col = q, state stays in-lane.
__global__ __launch_bounds__(64) void attn_fwd(
    const u16* __restrict__ Qp, const u16* __restrict__ Kp,
    const u16* __restrict__ Vt, const float* __restrict__ mask,
    u16* __restrict__ ctx) {
  const int b = blockIdx.z, h = blockIdx.y;
  const int lane = threadIdx.x & 63;
  const int l31 = lane & 31, hi = lane >> 5;
  const int q0 = blockIdx.x * 32;

  __shared__ __align__(16) u16 Plds[32][72];  // 144B rows (16B-aligned)

  const u16* Qb = Qp + (size_t)(b * SEQ + q0) * D_MODEL + h * DKH;
  const u16* Kb = Kp + (size_t)(b * SEQ) * D_MODEL + h * DKH;
  const u16* Vb = Vt + (size_t)(b * NHEADS + h) * DKH * SEQ;
  const float* mb = mask + (size_t)b * SEQ;

  us8 qf[4];
#pragma unroll
  for (int s = 0; s < 4; s++)
    qf[s] = *(const us8*)(Qb + (size_t)l31 * D_MODEL + s * 16 + hi * 8);

  float mrow = -1e30f, lsum = 0.f;
  f32x16 o0 = {}, o1 = {};

  for (int j0 = 0; j0 < SEQ; j0 += 32) {
    // S^T[kv][q], dk = 64 -> 4 MFMAs
    f32x16 st = {};
#pragma unroll
    for (int s = 0; s < 4; s++) {
      us8 kf = *(const us8*)(Kb + (size_t)(j0 + l31) * D_MODEL + s * 16 + hi * 8);
      st = mfma32(kf, qf[s], st);
    }
    // scale + mask; lane's kv(r) = (r&3) + 8*(r>>2) + 4*hi
    float4 mq[4];
#pragma unroll
    for (int t2 = 0; t2 < 4; t2++)
      mq[t2] = *(const float4*)(mb + j0 + 8 * t2 + 4 * hi);
    float sc[16];
#pragma unroll
    for (int r = 0; r < 16; r++) {
      const float* mqf = (const float*)&mq[r >> 2];
      sc[r] = fmaf(st[r], 0.125f, mqf[r & 3] * -1e9f);
    }
    // max: in-lane tree + one cross-half shfl
    float mx01 = fmaxf(sc[0], sc[1]),   mx23 = fmaxf(sc[2], sc[3]);
    float mx45 = fmaxf(sc[4], sc[5]),   mx67 = fmaxf(sc[6], sc[7]);
    float mx89 = fmaxf(sc[8], sc[9]),   mxab = fmaxf(sc[10], sc[11]);
    float mxcd = fmaxf(sc[12], sc[13]), mxef = fmaxf(sc[14], sc[15]);
    float mx = fmaxf(fmaxf(fmaxf(mx01, mx23), fmaxf(mx45, mx67)),
                     fmaxf(fmaxf(mx89, mxab), fmaxf(mxcd, mxef)));
    mx = fmaxf(mx, __shfl_xor(mx, 32));
    const float mnew = fmaxf(mrow, mx);
    const float corr = __expf(mrow - mnew);
    mrow = mnew;
    // exp + sum
    float p[16];
#pragma unroll
    for (int r = 0; r < 16; r++) p[r] = __expf(sc[r] - mnew);
    float rs = (((p[0] + p[1]) + (p[2] + p[3])) + ((p[4] + p[5]) + (p[6] + p[7])))
             + (((p[8] + p[9]) + (p[10] + p[11])) + ((p[12] + p[13]) + (p[14] + p[15])));
    rs += __shfl_xor(rs, 32);
    lsum = lsum * corr + rs;
    // rescale O^T
#pragma unroll
    for (int r = 0; r < 16; r++) { o0[r] *= corr; o1[r] *= corr; }
    // P^T -> B-fragments: pack bf16 pairs, cross-half shfl, select
    u32 w[8], sw[8];
#pragma unroll
    for (int t = 0; t < 8; t++) w[t] = pack_bf16(p[2 * t], p[2 * t + 1]);
#pragma unroll
    for (int t = 0; t < 8; t++) sw[t] = (u32)__shfl_xor((int)w[t], 32);
    union { u32 uw[4]; us8 v; } pb0, pb1;
    pb0.uw[0] = hi ? sw[2] : w[0];  pb0.uw[1] = hi ? sw[3] : w[1];
    pb0.uw[2] = hi ? w[2] : sw[0];  pb0.uw[3] = hi ? w[3] : sw[1];
    pb1.uw[0] = hi ? sw[6] : w[4];  pb1.uw[1] = hi ? sw[7] : w[5];
    pb1.uw[2] = hi ? w[6] : sw[4];  pb1.uw[3] = hi ? w[7] : sw[5];
    // O^T += V^T · P^T   (d-block 0: rows 0-31 of V^T; d-block 1: rows 32-63)
    us8 vf00 = *(const us8*)(Vb + (size_t)l31 * SEQ + j0 + hi * 8);
    us8 vf01 = *(const us8*)(Vb + (size_t)l31 * SEQ + j0 + 16 + hi * 8);
    o0 = mfma32(vf00, pb0.v, o0);
    o0 = mfma32(vf01, pb1.v, o0);
    us8 vf10 = *(const us8*)(Vb + (size_t)(32 + l31) * SEQ + j0 + hi * 8);
    us8 vf11 = *(const us8*)(Vb + (size_t)(32 + l31) * SEQ + j0 + 16 + hi * 8);
    o1 = mfma32(vf10, pb0.v, o1);
    o1 = mfma32(vf11, pb1.v, o1);
  }

  const float inv = 1.0f / lsum;
  // O^T -> LDS; lane's d(r) = db*32 + (r&3) + 8*(r>>2) + 4*hi (pairs r=2t,2t+1)
#pragma unroll
  for (int t = 0; t < 8; t++) {
    const int r = 2 * t;
    const int d0 = (r & 3) + 8 * (r >> 2) + 4 * hi;
    *(u32*)&Plds[l31][d0]      = pack_bf16(o0[r] * inv, o0[r + 1] * inv);
    *(u32*)&Plds[l31][32 + d0] = pack_bf16(o1[r] * inv, o1[r + 1] * inv);
  }
  __syncthreads();
  u16* op = ctx + (size_t)(b * SEQ + q0) * D_MODEL + h * DKH;
#pragma unroll
  for (int pass = 0; pass < 4; pass++) {
    const int row = pass * 8 + (lane >> 3);
    const int c = (lane & 7) * 8;
    us8 vv = *(const us8*)&Plds[row][c];
    *(us8*)(op + (size_t)row * D_MODEL + c) = vv;
  }
}

// ---------------------------------------------------------------------------
extern "C" void kernel_launch(void* const* d_in, const int* in_sizes, int n_in,
                              void* d_out, int out_size, void* d_ws, size_t ws_size,
                              hipStream_t stream) {
  const float* query = (const float*)d_in[0];
  const float* key   = (const float*)d_in[1];
  const float* value = (const float*)d_in[2];
  const float* mask  = (const float*)d_in[3];
  const float* Wq = (const float*)d_in[4];  const float* bq = (const float*)d_in[5];
  const float* Wk = (const float*)d_in[6];  const float* bk = (const float*)d_in[7];
  const float* Wv = (const float*)d_in[8];  const float* bv = (const float*)d_in[9];
  const float* Wo = (const float*)d_in[10]; const float* bo = (const float*)d_in[11];
  float* out = (float*)d_out;

  const size_t MB = 1ull << 20;
  char* ws = (char*)d_ws;
  u16* wtq = (u16*)(ws + 0 * MB);
  u16* wtk = (u16*)(ws + 2 * MB);
  u16* wtv = (u16*)(ws + 4 * MB);
  u16* wto = (u16*)(ws + 6 * MB);
  u16* Qp  = (u16*)(ws + 8 * MB);
  u16* Kp  = (u16*)(ws + 24 * MB);
  u16* ctx = (u16*)(ws + 40 * MB);
  u16* Vp = (u16*)d_out;                         // dead before final GEMM
  u16* Vt = Vp + (size_t)MTOT * D_MODEL;

  transpose_cvt_w<<<dim3(32, 32), 256, 0, stream>>>(Wq, wtq, D_MODEL, D_MODEL);
  transpose_cvt_w<<<dim3(32, 32), 256, 0, stream>>>(Wk, wtk, D_MODEL, D_MODEL);
  transpose_cvt_w<<<dim3(32, 32), 256, 0, stream>>>(Wv, wtv, D_MODEL, D_MODEL);
  transpose_cvt_w<<<dim3(32, 32), 256, 0, stream>>>(Wo, wto, D_MODEL, D_MODEL);

  dim3 ggrid(MTOT / 128, D_MODEL / 128);
  gemm_bt<true, false><<<ggrid, 256, 0, stream>>>((const void*)query, wtq, bq, (void*)Qp, D_MODEL, D_MODEL);
  gemm_bt<true, false><<<ggrid, 256, 0, stream>>>((const void*)key,   wtk, bk, (void*)Kp, D_MODEL, D_MODEL);
  gemm_bt<true, false><<<ggrid, 256, 0, stream>>>((const void*)value, wtv, bv, (void*)Vp, D_MODEL, D_MODEL);

  transpose_v_kernel<<<dim3(D_MODEL / 32, SEQ / 32, BATCH), 256, 0, stream>>>(Vp, Vt);

  attn_fwd<<<dim3(SEQ / 32, NHEADS, BATCH), 64, 0, stream>>>(Qp, Kp, Vt, mask, ctx);

  gemm_bt<false, true><<<ggrid, 256, 0, stream>>>((const void*)ctx, wto, bo, (void*)out, D_MODEL, D_MODEL);
}